// Round 16
// baseline (141.570 us; speedup 1.0000x reference)
//
#include <hip/hip_runtime.h>

// LRGCN cell on MI355X — 2-launch design:
//   L1 fused : [partw role, blocks 0..255: bucket (src,dst) by dst>>6 into
//               wave-private pair regions, 2 segs/block with wave-pairs
//               sharing one LDS hist/cursor (r16: halves LDS 25->12.5KB so
//               proj-role occupancy is wave-limited, not LDS-limited)]  ∥
//              [proj role: mx/root bf16-interleaved, pipelined weight loads].
//   L2 hub   : one block per 64-node bucket, XCD-chunked swizzle, 64-lane
//              wave scan: collect pairs -> LDS deg/rowptr/csr (int LDS
//              atomics; f32 LDS atomics ~7x slower, r13) -> shfl-gather
//              mxb -> LSTM -> out.
//
// Interleaved layout: stored[4j+t] = natural[16t+j]  (j=hidden unit, t=gate).
// mean_agg(x)@W == mean_agg(x@W) (linearity) makes pre-projection valid.
// Placement order within a bucket run is nondeterministic (2 waves share a
// cursor) — harmless: hub reduces the run with +, order-free to ulp.
//
// Inputs: 0 x[N,64] f32 | 1 ei[2,E] i32 | 2 ew[E] (unused) | 3 h0[N,16]
// | 4 c0[N,16] | 5 Wx[4,64,16] | 6 Rx | 7 bx[4,16] | 8 Wh[4,16,16] | 9 Rh
// | 10 bh | 11 lin_w[16] | 12 lin_b[1]
// Output: concat( out[N], h_new[N*16], c_new[N*16] ) f32

#define F_IN 64
#define NHID 16
#define BSH  6               // bucket shift: 64 nodes/bucket
#define NPB  64              // nodes per bucket
#define SEGW 512             // partition wave-segments
#define PARTB (SEGW / 2)     // partw-role blocks (2 segs each, 2 waves/seg)
#define EMAX 1280            // per-bucket edge capacity (mean ~1024, +8 sigma)

__device__ __forceinline__ unsigned pack_bf16x2(float lo, float hi) {
    unsigned a = __float_as_uint(lo);
    unsigned b = __float_as_uint(hi);
    a = (a + 0x7fffu + ((a >> 16) & 1u)) >> 16;
    b = (b + 0x7fffu + ((b >> 16) & 1u)) >> 16;
    return a | (b << 16);
}
__device__ __forceinline__ float fast_sigmoid(float v) {
    return 1.f / (1.f + __expf(-v));
}
__device__ __forceinline__ float fast_tanh(float v) {
    return 1.f - 2.f / (1.f + __expf(2.f * v));
}
__device__ __forceinline__ void fma4(float4& a, float s, const float4& wv) {
    a.x += s * wv.x; a.y += s * wv.y; a.z += s * wv.z; a.w += s * wv.w;
}

// ---------------- L1: fused [partw | proj] ----------------
// dynamic LDS: max(2*nbktp*4 bytes, 32*68*4 + 32*20*4 bytes)
__global__ __launch_bounds__(256) void fused_pp2(
        const int* __restrict__ ei, uint2* __restrict__ pairs,
        int* __restrict__ cnts, int E, int epw, int nbkt, int nbktp,
        const float* __restrict__ x, const float* __restrict__ h0,
        const float* __restrict__ Wx, const float* __restrict__ Wh,
        const float* __restrict__ Rx, const float* __restrict__ Rh,
        const float* __restrict__ bx, const float* __restrict__ bh,
        unsigned* __restrict__ mxb, unsigned* __restrict__ rootb,
        int n, int partBlocks) {
    extern __shared__ char smem[];
    int tid = threadIdx.x;

    if ((int)blockIdx.x < partBlocks) {
        // ======== partw role: 2 segments, 2 waves per segment ========
        int* cnt_s = (int*)smem;
        int wv = tid >> 6, lane = tid & 63;
        int half = wv >> 1;                 // which segment (0/1)
        int sub  = wv & 1;                  // wave within the pair
        int seg = blockIdx.x * 2 + half;
        int* cnt = cnt_s + half * nbktp;

        // zero (both waves of the pair cover the array)
        for (int i = sub * 64 + lane; i < nbktp; i += 128) cnt[i] = 0;
        __syncthreads();

        int beg = seg * epw;
        int end = beg + epw; if (end > E) end = E;

        // pass 1: histogram by bucket (both waves of the pair)
        for (int e = beg + sub * 64 + lane; e < end; e += 128)
            atomicAdd(&cnt[((unsigned)ei[E + e]) >> BSH], 1);
        __syncthreads();

        // wave-exclusive scan over cnt[0..nbkt) by the pair's first wave
        if (sub == 0) {
            int per = (nbkt + 63) >> 6;
            int s0 = lane * per;
            int s1 = s0 + per; if (s1 > nbkt) s1 = nbkt;
            if (s0 > nbkt) s0 = nbkt;
            int sum = 0;
            for (int i = s0; i < s1; ++i) sum += cnt[i];
            int inc = sum;
#pragma unroll
            for (int off = 1; off < 64; off <<= 1) {
                int v = __shfl_up(inc, off);
                if (lane >= off) inc += v;
            }
            int run = inc - sum;
            for (int i = s0; i < s1; ++i) { int c = cnt[i]; cnt[i] = run; run += c; }
            if (lane == 63) cnt[nbkt] = run;
        }
        __syncthreads();

        // publish offsets (coalesced, both waves)
        for (int i = sub * 64 + lane; i <= nbkt; i += 128)
            cnts[(size_t)seg * nbktp + i] = cnt[i];

        // pass 2: placement into the segment's region (shared cursor; order
        // within a bucket run is arbitrary — hub's reduction is order-free)
        uint2* wreg = pairs + (size_t)seg * epw;
        for (int e = beg + sub * 64 + lane; e < end; e += 128) {
            unsigned s = (unsigned)ei[e];
            unsigned d = (unsigned)ei[E + e];
            int pos = atomicAdd(&cnt[d >> BSH], 1);
            wreg[pos] = make_uint2(s, d);
        }
        return;
    }

    // ======== proj role: 32 nodes/block, 2 nodes per 16-lane group ========
    float* sx = (float*)smem;            // 32*68 floats
    float* sh = sx + 32 * 68;            // 32*20 floats
    int nodeBase = ((int)blockIdx.x - partBlocks) * 32;

#pragma unroll
    for (int i = 0; i < 2; ++i) {
        int idx = i * 256 + tid;
        int row = idx >> 4, c4 = idx & 15;
        int node = nodeBase + row;
        float4 v = make_float4(0.f, 0.f, 0.f, 0.f);
        if (node < n) v = ((const float4*)(x + (size_t)node * F_IN))[c4];
        *(float4*)(sx + row * 68 + c4 * 4) = v;
    }
    if (tid < 128) {
        int row = tid >> 2, c4 = tid & 3;
        int node = nodeBase + row;
        float4 v = make_float4(0.f, 0.f, 0.f, 0.f);
        if (node < n) v = ((const float4*)(h0 + (size_t)node * NHID))[c4];
        *(float4*)(sh + row * 20 + c4 * 4) = v;
    }
    __syncthreads();

    int grp = tid >> 4, q = tid & 15;
    int g = q >> 2, rr = q & 3;
    const float* wxp = Wx + g * (F_IN * NHID) + rr * 4;
    const float* rxp = Rx + g * (F_IN * NHID) + rr * 4;
    const float* whp = Wh + g * (NHID * NHID) + rr * 4;
    const float* rhp = Rh + g * (NHID * NHID) + rr * 4;
    const float* sx0 = sx + (grp * 2) * 68;
    const float* sx1 = sx0 + 68;
    const float* sh0 = sh + (grp * 2) * 20;
    const float* sh1 = sh0 + 20;

    float4 m0 = make_float4(0.f, 0.f, 0.f, 0.f), m1 = m0, r0 = m0, r1 = m0;

    // --- x-loop: software pipeline on weight loads ---
    float4 w0 = *(const float4*)(wxp + 0 * NHID);
    float4 w1 = *(const float4*)(wxp + 1 * NHID);
    float4 w2 = *(const float4*)(wxp + 2 * NHID);
    float4 w3 = *(const float4*)(wxp + 3 * NHID);
    float4 v0 = *(const float4*)(rxp + 0 * NHID);
    float4 v1 = *(const float4*)(rxp + 1 * NHID);
    float4 v2 = *(const float4*)(rxp + 2 * NHID);
    float4 v3 = *(const float4*)(rxp + 3 * NHID);
#pragma unroll 1
    for (int k = 0; k < F_IN; k += 4) {
        float4 xa = *(const float4*)(sx0 + k);
        float4 xb = *(const float4*)(sx1 + k);
        int kn = (k + 4 < F_IN) ? k + 4 : 0;   // last-iter prefetch is harmless
        float4 t0 = *(const float4*)(wxp + (kn + 0) * NHID);
        float4 t1 = *(const float4*)(wxp + (kn + 1) * NHID);
        float4 t2 = *(const float4*)(wxp + (kn + 2) * NHID);
        float4 t3 = *(const float4*)(wxp + (kn + 3) * NHID);
        float4 u0 = *(const float4*)(rxp + (kn + 0) * NHID);
        float4 u1 = *(const float4*)(rxp + (kn + 1) * NHID);
        float4 u2 = *(const float4*)(rxp + (kn + 2) * NHID);
        float4 u3 = *(const float4*)(rxp + (kn + 3) * NHID);
        fma4(m0, xa.x, w0); fma4(m0, xa.y, w1); fma4(m0, xa.z, w2); fma4(m0, xa.w, w3);
        fma4(m1, xb.x, w0); fma4(m1, xb.y, w1); fma4(m1, xb.z, w2); fma4(m1, xb.w, w3);
        fma4(r0, xa.x, v0); fma4(r0, xa.y, v1); fma4(r0, xa.z, v2); fma4(r0, xa.w, v3);
        fma4(r1, xb.x, v0); fma4(r1, xb.y, v1); fma4(r1, xb.z, v2); fma4(r1, xb.w, v3);
        w0 = t0; w1 = t1; w2 = t2; w3 = t3;
        v0 = u0; v1 = u1; v2 = u2; v3 = u3;
    }
    // --- h-loop (short; pipelined the same way) ---
    w0 = *(const float4*)(whp + 0 * NHID);
    w1 = *(const float4*)(whp + 1 * NHID);
    w2 = *(const float4*)(whp + 2 * NHID);
    w3 = *(const float4*)(whp + 3 * NHID);
    v0 = *(const float4*)(rhp + 0 * NHID);
    v1 = *(const float4*)(rhp + 1 * NHID);
    v2 = *(const float4*)(rhp + 2 * NHID);
    v3 = *(const float4*)(rhp + 3 * NHID);
#pragma unroll 1
    for (int k = 0; k < NHID; k += 4) {
        float4 xa = *(const float4*)(sh0 + k);
        float4 xb = *(const float4*)(sh1 + k);
        int kn = (k + 4 < NHID) ? k + 4 : 0;
        float4 t0 = *(const float4*)(whp + (kn + 0) * NHID);
        float4 t1 = *(const float4*)(whp + (kn + 1) * NHID);
        float4 t2 = *(const float4*)(whp + (kn + 2) * NHID);
        float4 t3 = *(const float4*)(whp + (kn + 3) * NHID);
        float4 u0 = *(const float4*)(rhp + (kn + 0) * NHID);
        float4 u1 = *(const float4*)(rhp + (kn + 1) * NHID);
        float4 u2 = *(const float4*)(rhp + (kn + 2) * NHID);
        float4 u3 = *(const float4*)(rhp + (kn + 3) * NHID);
        fma4(m0, xa.x, w0); fma4(m0, xa.y, w1); fma4(m0, xa.z, w2); fma4(m0, xa.w, w3);
        fma4(m1, xb.x, w0); fma4(m1, xb.y, w1); fma4(m1, xb.z, w2); fma4(m1, xb.w, w3);
        fma4(r0, xa.x, v0); fma4(r0, xa.y, v1); fma4(r0, xa.z, v2); fma4(r0, xa.w, v3);
        fma4(r1, xb.x, v0); fma4(r1, xb.y, v1); fma4(r1, xb.z, v2); fma4(r1, xb.w, v3);
        w0 = t0; w1 = t1; w2 = t2; w3 = t3;
        v0 = u0; v1 = u1; v2 = u2; v3 = u3;
    }
    {   // biases into root (natural cols 4q..4q+3)
        float4 b1 = *(const float4*)(bx + q * 4);
        float4 b2 = *(const float4*)(bh + q * 4);
        float bxx = b1.x + b2.x, byy = b1.y + b2.y;
        float bzz = b1.z + b2.z, bww = b1.w + b2.w;
        r0.x += bxx; r0.y += byy; r0.z += bzz; r0.w += bww;
        r1.x += bxx; r1.y += byy; r1.z += bzz; r1.w += bww;
    }

    // transpose natural -> interleaved via LDS, store bf16
    __syncthreads();
    *(float4*)(sx + (grp * 2 + 0) * 68 + q * 4) = m0;
    *(float4*)(sx + (grp * 2 + 1) * 68 + q * 4) = m1;
    __syncthreads();
#pragma unroll
    for (int i = 0; i < 2; ++i) {
        int node = nodeBase + grp * 2 + i;
        if (node < n) {
            const float* rowp = sx + (grp * 2 + i) * 68;
            float a0 = rowp[q], a1 = rowp[16 + q], a2 = rowp[32 + q], a3 = rowp[48 + q];
            ((uint2*)(mxb + (size_t)node * 32))[q] =
                make_uint2(pack_bf16x2(a0, a1), pack_bf16x2(a2, a3));
        }
    }
    if (rootb != nullptr) {
        __syncthreads();
        *(float4*)(sx + (grp * 2 + 0) * 68 + q * 4) = r0;
        *(float4*)(sx + (grp * 2 + 1) * 68 + q * 4) = r1;
        __syncthreads();
#pragma unroll
        for (int i = 0; i < 2; ++i) {
            int node = nodeBase + grp * 2 + i;
            if (node < n) {
                const float* rowp = sx + (grp * 2 + i) * 68;
                float a0 = rowp[q], a1 = rowp[16 + q], a2 = rowp[32 + q], a3 = rowp[48 + q];
                ((uint2*)(rootb + (size_t)node * 32))[q] =
                    make_uint2(pack_bf16x2(a0, a1), pack_bf16x2(a2, a3));
            }
        }
    }
}

// ---------------- L2: per-bucket hub (LDS CSR + gather + LSTM) ----------------
__global__ __launch_bounds__(256) void hub_kernel(
        const float* __restrict__ c0, const float* __restrict__ lin_w,
        const float* __restrict__ lin_b,
        const unsigned* __restrict__ mxb, const unsigned* __restrict__ rootb,
        const uint2* __restrict__ pairs, const int* __restrict__ cnts,
        float* __restrict__ out, int n, int epw, int nbktp) {
    __shared__ int deg[NPB], rowptr[NPB], cursor[NPB];
    __shared__ unsigned stage[EMAX];
    __shared__ int csr[EMAX];
    __shared__ int scnt;
    int tid = threadIdx.x;

    // XCD-chunked bucket swizzle (bijective): consecutive buckets -> same XCD.
    int nb = gridDim.x;
    int qq = nb >> 3, rr2 = nb & 7;
    int xcd = blockIdx.x & 7, ix = blockIdx.x >> 3;
    int b = (xcd < rr2) ? xcd * (qq + 1) + ix
                        : rr2 * (qq + 1) + (xcd - rr2) * qq + ix;
    int nstart = b << BSH;

    if (tid < NPB) deg[tid] = 0;
    if (tid == 0) scnt = 0;
    __syncthreads();

    // phase 1: collect this bucket's edges (SEGW=512 segs, 2 per thread)
    int seg0 = tid, seg1 = tid + 256;
    const int* cr0 = cnts + (size_t)seg0 * nbktp;
    const int* cr1 = cnts + (size_t)seg1 * nbktp;
    int o1a = cr0[b], o2a = cr0[b + 1];
    int o1b = cr1[b], o2b = cr1[b + 1];
    int tot = (o2a - o1a) + (o2b - o1b);
    int idx = 0;
    if (tot > 0) idx = atomicAdd(&scnt, tot);
    {
        const uint2* p = pairs + (size_t)seg0 * epw;
        for (int i = o1a; i < o2a; ++i, ++idx) {
            uint2 pr = p[i];
            if (idx < EMAX) {
                int dl = (int)pr.y - nstart;
                stage[idx] = pr.x | ((unsigned)dl << 26);
                atomicAdd(&deg[dl], 1);
            }
        }
        p = pairs + (size_t)seg1 * epw;
        for (int i = o1b; i < o2b; ++i, ++idx) {
            uint2 pr = p[i];
            if (idx < EMAX) {
                int dl = (int)pr.y - nstart;
                stage[idx] = pr.x | ((unsigned)dl << 26);
                atomicAdd(&deg[dl], 1);
            }
        }
    }
    __syncthreads();

    // phase 2: 64-lane wave scan over deg[0..63]
    if (tid < 64) {
        int lane = tid;
        int v = deg[lane];
        int inc = v;
#pragma unroll
        for (int off = 1; off < 64; off <<= 1) {
            int t = __shfl_up(inc, off);
            if (lane >= off) inc += t;
        }
        rowptr[lane] = inc - v;
        cursor[lane] = inc - v;
    }
    __syncthreads();

    // phase 3: place into LDS csr (int LDS atomics — cheap)
    int sc = scnt < EMAX ? scnt : EMAX;
    for (int i = tid; i < sc; i += 256) {
        unsigned v = stage[i];
        int dl = v >> 26;
        int pos = atomicAdd(&cursor[dl], 1);
        csr[pos] = (int)(v & 0x03FFFFFFu);
    }
    __syncthreads();

    // phase 4: gather + LSTM + head.  16 groups x 16 lanes; 4 nodes/group.
    int grp = tid >> 4, q = tid & 15;
    for (int ln = grp; ln < NPB; ln += 16) {
        int node = nstart + ln;
        if (node >= n) continue;
        int cnt = deg[ln];
        const int* row = &csr[rowptr[ln]];

        float ax = 0.f, ay = 0.f, az = 0.f, aw = 0.f;
        int base = 0;
        for (; base + 16 <= cnt; base += 16) {
            int eid = row[base + q];
#pragma unroll
            for (int k = 0; k < 16; ++k) {
                int s = __shfl(eid, k, 16);
                uint2 v = *((const uint2*)(mxb + (size_t)s * 32) + q);
                ax += __uint_as_float(v.x << 16);
                ay += __uint_as_float(v.x & 0xffff0000u);
                az += __uint_as_float(v.y << 16);
                aw += __uint_as_float(v.y & 0xffff0000u);
            }
        }
        int m = cnt - base;
        if (m > 0) {
            int eid = (q < m) ? row[base + q] : 0;
            for (int k = 0; k < m; ++k) {
                int s = __shfl(eid, k, 16);
                uint2 v = *((const uint2*)(mxb + (size_t)s * 32) + q);
                ax += __uint_as_float(v.x << 16);
                ay += __uint_as_float(v.x & 0xffff0000u);
                az += __uint_as_float(v.y << 16);
                aw += __uint_as_float(v.y & 0xffff0000u);
            }
        }

        uint2 rv = *((const uint2*)(rootb + (size_t)node * 32) + q);
        float inv = 1.f / fmaxf((float)cnt, 1.f);
        float px = ax * inv + __uint_as_float(rv.x << 16);
        float py = ay * inv + __uint_as_float(rv.x & 0xffff0000u);
        float pz = az * inv + __uint_as_float(rv.y << 16);
        float pw = aw * inv + __uint_as_float(rv.y & 0xffff0000u);

        float ig = fast_sigmoid(px);
        float fg = fast_sigmoid(py);
        float tg = fast_tanh(pz);
        float og = fast_sigmoid(pw);

        float cn = fg * c0[(size_t)node * NHID + q] + ig * tg;
        float hn = og * fast_tanh(cn);

        out[(size_t)n + (size_t)node * NHID + q] = hn;
        out[(size_t)n + (size_t)n * NHID + (size_t)node * NHID + q] = cn;

        float p = fmaxf(hn, 0.f) * lin_w[q];
#pragma unroll
        for (int off = 8; off; off >>= 1) p += __shfl_xor(p, off, 16);
        if (q == 0) out[node] = p + lin_b[0];
    }
}

// ---------------- fallback path (ws too small) ----------------
__global__ void zero_int_kernel(int4* __restrict__ p, int n4) {
    int i = blockIdx.x * blockDim.x + threadIdx.x;
    if (i < n4) p[i] = make_int4(0, 0, 0, 0);
}
__global__ void scatter_direct_kernel(const int* __restrict__ ei,
                                      int* __restrict__ cursor,
                                      int* __restrict__ csrp, int E, int cap) {
    int e = blockIdx.x * blockDim.x + threadIdx.x;
    if (e < E) {
        int d = ei[E + e];
        int pos = atomicAdd(&cursor[d], 1);
        if (pos < cap) csrp[(size_t)d * cap + pos] = ei[e];
    }
}
__global__ __launch_bounds__(256) void gfinal_inl(
        const float* __restrict__ x, const float* __restrict__ h0,
        const float* __restrict__ c0,
        const float* __restrict__ Rx, const float* __restrict__ Rh,
        const float* __restrict__ bx, const float* __restrict__ bh,
        const float* __restrict__ lin_w, const float* __restrict__ lin_b,
        const unsigned* __restrict__ mxb, const int* __restrict__ csrp,
        const int* __restrict__ cursor,
        float* __restrict__ out, int n, int cap) {
    __shared__ float sm[16 * 68];
    int idx = blockIdx.x * 256 + threadIdx.x;
    int node = idx >> 4, q = idx & 15;
    int nl = threadIdx.x >> 4;
    bool valid = node < n;

    int cnt = 0;
    if (valid) cnt = cursor[node];
    int mt = cnt < cap ? cnt : cap;
    const int* row = csrp + (size_t)node * cap;

    float ax = 0.f, ay = 0.f, az = 0.f, aw = 0.f;
    int base = 0;
    for (; base + 16 <= mt; base += 16) {
        int eid = row[base + q];
#pragma unroll
        for (int k = 0; k < 16; ++k) {
            int s = __shfl(eid, k, 16);
            uint2 v = *((const uint2*)(mxb + (size_t)s * 32) + q);
            ax += __uint_as_float(v.x << 16);
            ay += __uint_as_float(v.x & 0xffff0000u);
            az += __uint_as_float(v.y << 16);
            aw += __uint_as_float(v.y & 0xffff0000u);
        }
    }
    int mrem = mt - base;
    if (mrem > 0) {
        int eid = (q < mrem) ? row[base + q] : 0;
        for (int k = 0; k < mrem; ++k) {
            int s = __shfl(eid, k, 16);
            uint2 v = *((const uint2*)(mxb + (size_t)s * 32) + q);
            ax += __uint_as_float(v.x << 16);
            ay += __uint_as_float(v.x & 0xffff0000u);
            az += __uint_as_float(v.y << 16);
            aw += __uint_as_float(v.y & 0xffff0000u);
        }
    }

    float4 r = make_float4(0.f, 0.f, 0.f, 0.f);
    if (valid) {
        int g = q >> 2, rr = q & 3;
        const float* xr = x + (size_t)node * F_IN;
        const float* hr = h0 + (size_t)node * NHID;
        const float* rx = Rx + g * (F_IN * NHID) + rr * 4;
        const float* rh = Rh + g * (NHID * NHID) + rr * 4;
#pragma unroll 8
        for (int k = 0; k < F_IN; ++k) fma4(r, xr[k], *(const float4*)(rx + k * NHID));
#pragma unroll
        for (int k = 0; k < NHID; ++k) fma4(r, hr[k], *(const float4*)(rh + k * NHID));
        float4 b1 = *(const float4*)(bx + q * 4);
        float4 b2 = *(const float4*)(bh + q * 4);
        r.x += b1.x + b2.x; r.y += b1.y + b2.y;
        r.z += b1.z + b2.z; r.w += b1.w + b2.w;
    }
    *(float4*)(sm + nl * 68 + q * 4) = r;
    __syncthreads();

    if (valid) {
        const float* rowp = sm + nl * 68;
        float inv = 1.f / fmaxf((float)cnt, 1.f);
        float px = ax * inv + rowp[q];
        float py = ay * inv + rowp[16 + q];
        float pz = az * inv + rowp[32 + q];
        float pw = aw * inv + rowp[48 + q];
        float ig = fast_sigmoid(px);
        float fg = fast_sigmoid(py);
        float tg = fast_tanh(pz);
        float og = fast_sigmoid(pw);
        float cn = fg * c0[(size_t)node * NHID + q] + ig * tg;
        float hn = og * fast_tanh(cn);
        out[(size_t)n + (size_t)node * NHID + q] = hn;
        out[(size_t)n + (size_t)n * NHID + (size_t)node * NHID + q] = cn;
        float p = fmaxf(hn, 0.f) * lin_w[q];
#pragma unroll
        for (int off = 8; off; off >>= 1) p += __shfl_xor(p, off, 16);
        if (q == 0) out[node] = p + lin_b[0];
    }
}

extern "C" void kernel_launch(void* const* d_in, const int* in_sizes, int n_in,
                              void* d_out, int out_size, void* d_ws, size_t ws_size,
                              hipStream_t stream) {
    const float* x     = (const float*)d_in[0];
    const int*   ei    = (const int*)d_in[1];
    const float* h0    = (const float*)d_in[3];
    const float* c0    = (const float*)d_in[4];
    const float* Wx    = (const float*)d_in[5];
    const float* Rx    = (const float*)d_in[6];
    const float* bx    = (const float*)d_in[7];
    const float* Wh    = (const float*)d_in[8];
    const float* Rh    = (const float*)d_in[9];
    const float* bh    = (const float*)d_in[10];
    const float* lin_w = (const float*)d_in[11];
    const float* lin_b = (const float*)d_in[12];

    const int N = in_sizes[3] / NHID;
    const int E = in_sizes[1] / 2;
    const int NBKT  = (N + NPB - 1) >> BSH;           // 1563 for N=100000
    const int nbktp = ((NBKT + 1) + 15) & ~15;        // 1568
    const int epw   = ((E + SEGW - 1) / SEGW + 7) & ~7;

    // u32 units
    const size_t mxb_u   = (size_t)N * 32;
    const size_t root_u  = (size_t)N * 32;
    const size_t pairs_u = 2ull * SEGW * epw;
    const size_t cnts_u  = (size_t)SEGW * nbktp;
    const size_t need = (mxb_u + root_u + pairs_u + cnts_u) * 4;

    unsigned* wsu = (unsigned*)d_ws;
    float* out = (float*)d_out;
    const int projBlocks = (N + 31) / 32;

    // dynamic LDS for fused kernel: max(partw 2*nbktp*4, proj 32*68*4+32*20*4)
    size_t ldsPart = (size_t)2 * nbktp * sizeof(int);
    size_t ldsProj = (32 * 68 + 32 * 20) * sizeof(float);
    size_t ldsFused = ldsPart > ldsProj ? ldsPart : ldsProj;

    if (ws_size >= need) {
        unsigned* mxb   = wsu;
        unsigned* rootb = mxb + mxb_u;
        uint2*    pairs = (uint2*)(rootb + root_u);
        int*      cnts  = (int*)(pairs + (size_t)SEGW * epw);

        fused_pp2<<<PARTB + projBlocks, 256, (int)ldsFused, stream>>>(
            ei, pairs, cnts, E, epw, NBKT, nbktp,
            x, h0, Wx, Wh, Rx, Rh, bx, bh, mxb, rootb, N, PARTB);
        hub_kernel<<<NBKT, 256, 0, stream>>>(
            c0, lin_w, lin_b, mxb, rootb, pairs, cnts, out, N, epw, nbktp);
    } else {
        const int cap = 32;
        const int P = (N + 3) & ~3;
        unsigned* mxb   = wsu;
        int*      cursor= (int*)(mxb + mxb_u);
        int*      csrp  = cursor + P;

        zero_int_kernel<<<(P / 4 + 255) / 256, 256, 0, stream>>>((int4*)cursor, P / 4);
        fused_pp2<<<projBlocks, 256, (int)ldsProj, stream>>>(
            ei, nullptr, nullptr, E, epw, NBKT, nbktp,
            x, h0, Wx, Wh, Rx, Rh, bx, bh, mxb, nullptr, N, 0);
        scatter_direct_kernel<<<(E + 255) / 256, 256, 0, stream>>>(
            ei, cursor, csrp, E, cap);
        gfinal_inl<<<(N * 16 + 255) / 256, 256, 0, stream>>>(
            x, h0, c0, Rx, Rh, bx, bh, lin_w, lin_b, mxb, csrp, cursor,
            out, N, cap);
    }
}

// Round 17
// 140.334 us; speedup vs baseline: 1.0088x; 1.0088x over previous
//
#include <hip/hip_runtime.h>

// LRGCN cell on MI355X — 2-launch design (128-thread fused blocks):
//   L1 fused : [partw role, blocks 0..255: 2 waves, 1 seg/wave, LDS hist+scan
//               (r14-validated shape), bucket (src,dst) by dst>>6 into
//               wave-private pair regions]  ∥
//              [proj role: mx/root bf16-interleaved; r17: 4 nodes per 16-lane
//               group (8 groups/block) — doubles FMAs per weight load; r16
//               showed proj is L1-BW-bound on weight re-streaming (VALU 21%,
//               time invariant to occupancy)].
//   L2 hub   : one block per 64-node bucket, XCD-chunked swizzle, 64-lane
//              wave scan: collect pairs -> LDS deg/rowptr/csr (int LDS
//              atomics; f32 LDS atomics ~7x slower, r13) -> shfl-gather
//              mxb -> LSTM -> out.
//
// Interleaved layout: stored[4j+t] = natural[16t+j]  (j=hidden unit, t=gate).
// mean_agg(x)@W == mean_agg(x@W) (linearity) makes pre-projection valid.
//
// Inputs: 0 x[N,64] f32 | 1 ei[2,E] i32 | 2 ew[E] (unused) | 3 h0[N,16]
// | 4 c0[N,16] | 5 Wx[4,64,16] | 6 Rx | 7 bx[4,16] | 8 Wh[4,16,16] | 9 Rh
// | 10 bh | 11 lin_w[16] | 12 lin_b[1]
// Output: concat( out[N], h_new[N*16], c_new[N*16] ) f32

#define F_IN 64
#define NHID 16
#define BSH  6               // bucket shift: 64 nodes/bucket
#define NPB  64              // nodes per bucket
#define SEGW 512             // partition wave-segments
#define PARTB (SEGW / 2)     // partw-role blocks (2 waves, 1 seg each)
#define EMAX 1280            // per-bucket edge capacity (mean ~1024, +8 sigma)

__device__ __forceinline__ unsigned pack_bf16x2(float lo, float hi) {
    unsigned a = __float_as_uint(lo);
    unsigned b = __float_as_uint(hi);
    a = (a + 0x7fffu + ((a >> 16) & 1u)) >> 16;
    b = (b + 0x7fffu + ((b >> 16) & 1u)) >> 16;
    return a | (b << 16);
}
__device__ __forceinline__ float fast_sigmoid(float v) {
    return 1.f / (1.f + __expf(-v));
}
__device__ __forceinline__ float fast_tanh(float v) {
    return 1.f - 2.f / (1.f + __expf(2.f * v));
}
__device__ __forceinline__ void fma4(float4& a, float s, const float4& wv) {
    a.x += s * wv.x; a.y += s * wv.y; a.z += s * wv.z; a.w += s * wv.w;
}

// ---------------- L1: fused [partw | proj], 128 threads ----------------
// dynamic LDS: max(2*nbktp*4 bytes, 32*68*4 + 32*20*4 bytes)
__global__ __launch_bounds__(128) void fused_pp2(
        const int* __restrict__ ei, uint2* __restrict__ pairs,
        int* __restrict__ cnts, int E, int epw, int nbkt, int nbktp,
        const float* __restrict__ x, const float* __restrict__ h0,
        const float* __restrict__ Wx, const float* __restrict__ Wh,
        const float* __restrict__ Rx, const float* __restrict__ Rh,
        const float* __restrict__ bx, const float* __restrict__ bh,
        unsigned* __restrict__ mxb, unsigned* __restrict__ rootb,
        int n, int partBlocks) {
    extern __shared__ char smem[];
    int tid = threadIdx.x;

    if ((int)blockIdx.x < partBlocks) {
        // ======== partw role: 2 waves, one segment each (r14 shape) ========
        int* cnt_s = (int*)smem;
        int wv = tid >> 6, lane = tid & 63;
        int seg = blockIdx.x * 2 + wv;
        int* cnt = cnt_s + wv * nbktp;

        for (int i = lane; i < nbktp; i += 64) cnt[i] = 0;
        __syncthreads();

        int beg = seg * epw;
        int end = beg + epw; if (end > E) end = E;

        // pass 1: histogram by bucket
        for (int e = beg + lane; e < end; e += 64)
            atomicAdd(&cnt[((unsigned)ei[E + e]) >> BSH], 1);
        __syncthreads();

        // wave-exclusive scan over cnt[0..nbkt), total at cnt[nbkt]
        int per = (nbkt + 63) >> 6;
        int s0 = lane * per;
        int s1 = s0 + per; if (s1 > nbkt) s1 = nbkt;
        if (s0 > nbkt) s0 = nbkt;
        int sum = 0;
        for (int i = s0; i < s1; ++i) sum += cnt[i];
        int inc = sum;
#pragma unroll
        for (int off = 1; off < 64; off <<= 1) {
            int v = __shfl_up(inc, off);
            if (lane >= off) inc += v;
        }
        int run = inc - sum;
        for (int i = s0; i < s1; ++i) { int c = cnt[i]; cnt[i] = run; run += c; }
        if (lane == 63) cnt[nbkt] = run;
        __syncthreads();

        // publish offsets (coalesced)
        for (int i = lane; i <= nbkt; i += 64)
            cnts[(size_t)seg * nbktp + i] = cnt[i];

        // pass 2: placement into wave-private region (cnt[] now cursors)
        uint2* wreg = pairs + (size_t)seg * epw;
        for (int e = beg + lane; e < end; e += 64) {
            unsigned s = (unsigned)ei[e];
            unsigned d = (unsigned)ei[E + e];
            int pos = atomicAdd(&cnt[d >> BSH], 1);
            wreg[pos] = make_uint2(s, d);
        }
        return;
    }

    // ======== proj role: 32 nodes/block, 4 nodes per 16-lane group ========
    float* sx = (float*)smem;            // 32*68 floats
    float* sh = sx + 32 * 68;            // 32*20 floats
    int nodeBase = ((int)blockIdx.x - partBlocks) * 32;

#pragma unroll
    for (int i = 0; i < 4; ++i) {
        int idx = i * 128 + tid;
        int row = idx >> 4, c4 = idx & 15;
        int node = nodeBase + row;
        float4 v = make_float4(0.f, 0.f, 0.f, 0.f);
        if (node < n) v = ((const float4*)(x + (size_t)node * F_IN))[c4];
        *(float4*)(sx + row * 68 + c4 * 4) = v;
    }
    {
        int row = tid >> 2, c4 = tid & 3;
        int node = nodeBase + row;
        float4 v = make_float4(0.f, 0.f, 0.f, 0.f);
        if (node < n) v = ((const float4*)(h0 + (size_t)node * NHID))[c4];
        *(float4*)(sh + row * 20 + c4 * 4) = v;
    }
    __syncthreads();

    int grp = tid >> 4, q = tid & 15;    // grp 0..7
    int g = q >> 2, rr = q & 3;
    const float* wxp = Wx + g * (F_IN * NHID) + rr * 4;
    const float* rxp = Rx + g * (F_IN * NHID) + rr * 4;
    const float* whp = Wh + g * (NHID * NHID) + rr * 4;
    const float* rhp = Rh + g * (NHID * NHID) + rr * 4;
    const float* sx0 = sx + (grp * 4 + 0) * 68;
    const float* sx1 = sx + (grp * 4 + 1) * 68;
    const float* sx2 = sx + (grp * 4 + 2) * 68;
    const float* sx3 = sx + (grp * 4 + 3) * 68;
    const float* sh0 = sh + (grp * 4 + 0) * 20;
    const float* sh1 = sh + (grp * 4 + 1) * 20;
    const float* sh2 = sh + (grp * 4 + 2) * 20;
    const float* sh3 = sh + (grp * 4 + 3) * 20;

    float4 m0 = make_float4(0.f, 0.f, 0.f, 0.f), m1 = m0, m2 = m0, m3 = m0;
    float4 r0 = m0, r1 = m0, r2 = m0, r3 = m0;

    // --- x-loop: software pipeline on weight loads ---
    float4 w0 = *(const float4*)(wxp + 0 * NHID);
    float4 w1 = *(const float4*)(wxp + 1 * NHID);
    float4 w2 = *(const float4*)(wxp + 2 * NHID);
    float4 w3 = *(const float4*)(wxp + 3 * NHID);
    float4 v0 = *(const float4*)(rxp + 0 * NHID);
    float4 v1 = *(const float4*)(rxp + 1 * NHID);
    float4 v2 = *(const float4*)(rxp + 2 * NHID);
    float4 v3 = *(const float4*)(rxp + 3 * NHID);
#pragma unroll 1
    for (int k = 0; k < F_IN; k += 4) {
        float4 xa = *(const float4*)(sx0 + k);
        float4 xb = *(const float4*)(sx1 + k);
        float4 xc = *(const float4*)(sx2 + k);
        float4 xd = *(const float4*)(sx3 + k);
        int kn = (k + 4 < F_IN) ? k + 4 : 0;   // last-iter prefetch is harmless
        float4 t0 = *(const float4*)(wxp + (kn + 0) * NHID);
        float4 t1 = *(const float4*)(wxp + (kn + 1) * NHID);
        float4 t2 = *(const float4*)(wxp + (kn + 2) * NHID);
        float4 t3 = *(const float4*)(wxp + (kn + 3) * NHID);
        float4 u0 = *(const float4*)(rxp + (kn + 0) * NHID);
        float4 u1 = *(const float4*)(rxp + (kn + 1) * NHID);
        float4 u2 = *(const float4*)(rxp + (kn + 2) * NHID);
        float4 u3 = *(const float4*)(rxp + (kn + 3) * NHID);
        fma4(m0, xa.x, w0); fma4(m0, xa.y, w1); fma4(m0, xa.z, w2); fma4(m0, xa.w, w3);
        fma4(m1, xb.x, w0); fma4(m1, xb.y, w1); fma4(m1, xb.z, w2); fma4(m1, xb.w, w3);
        fma4(m2, xc.x, w0); fma4(m2, xc.y, w1); fma4(m2, xc.z, w2); fma4(m2, xc.w, w3);
        fma4(m3, xd.x, w0); fma4(m3, xd.y, w1); fma4(m3, xd.z, w2); fma4(m3, xd.w, w3);
        fma4(r0, xa.x, v0); fma4(r0, xa.y, v1); fma4(r0, xa.z, v2); fma4(r0, xa.w, v3);
        fma4(r1, xb.x, v0); fma4(r1, xb.y, v1); fma4(r1, xb.z, v2); fma4(r1, xb.w, v3);
        fma4(r2, xc.x, v0); fma4(r2, xc.y, v1); fma4(r2, xc.z, v2); fma4(r2, xc.w, v3);
        fma4(r3, xd.x, v0); fma4(r3, xd.y, v1); fma4(r3, xd.z, v2); fma4(r3, xd.w, v3);
        w0 = t0; w1 = t1; w2 = t2; w3 = t3;
        v0 = u0; v1 = u1; v2 = u2; v3 = u3;
    }
    // --- h-loop (short; same pipeline) ---
    w0 = *(const float4*)(whp + 0 * NHID);
    w1 = *(const float4*)(whp + 1 * NHID);
    w2 = *(const float4*)(whp + 2 * NHID);
    w3 = *(const float4*)(whp + 3 * NHID);
    v0 = *(const float4*)(rhp + 0 * NHID);
    v1 = *(const float4*)(rhp + 1 * NHID);
    v2 = *(const float4*)(rhp + 2 * NHID);
    v3 = *(const float4*)(rhp + 3 * NHID);
#pragma unroll 1
    for (int k = 0; k < NHID; k += 4) {
        float4 xa = *(const float4*)(sh0 + k);
        float4 xb = *(const float4*)(sh1 + k);
        float4 xc = *(const float4*)(sh2 + k);
        float4 xd = *(const float4*)(sh3 + k);
        int kn = (k + 4 < NHID) ? k + 4 : 0;
        float4 t0 = *(const float4*)(whp + (kn + 0) * NHID);
        float4 t1 = *(const float4*)(whp + (kn + 1) * NHID);
        float4 t2 = *(const float4*)(whp + (kn + 2) * NHID);
        float4 t3 = *(const float4*)(whp + (kn + 3) * NHID);
        float4 u0 = *(const float4*)(rhp + (kn + 0) * NHID);
        float4 u1 = *(const float4*)(rhp + (kn + 1) * NHID);
        float4 u2 = *(const float4*)(rhp + (kn + 2) * NHID);
        float4 u3 = *(const float4*)(rhp + (kn + 3) * NHID);
        fma4(m0, xa.x, w0); fma4(m0, xa.y, w1); fma4(m0, xa.z, w2); fma4(m0, xa.w, w3);
        fma4(m1, xb.x, w0); fma4(m1, xb.y, w1); fma4(m1, xb.z, w2); fma4(m1, xb.w, w3);
        fma4(m2, xc.x, w0); fma4(m2, xc.y, w1); fma4(m2, xc.z, w2); fma4(m2, xc.w, w3);
        fma4(m3, xd.x, w0); fma4(m3, xd.y, w1); fma4(m3, xd.z, w2); fma4(m3, xd.w, w3);
        fma4(r0, xa.x, v0); fma4(r0, xa.y, v1); fma4(r0, xa.z, v2); fma4(r0, xa.w, v3);
        fma4(r1, xb.x, v0); fma4(r1, xb.y, v1); fma4(r1, xb.z, v2); fma4(r1, xb.w, v3);
        fma4(r2, xc.x, v0); fma4(r2, xc.y, v1); fma4(r2, xc.z, v2); fma4(r2, xc.w, v3);
        fma4(r3, xd.x, v0); fma4(r3, xd.y, v1); fma4(r3, xd.z, v2); fma4(r3, xd.w, v3);
        w0 = t0; w1 = t1; w2 = t2; w3 = t3;
        v0 = u0; v1 = u1; v2 = u2; v3 = u3;
    }
    {   // biases into root (natural cols 4q..4q+3)
        float4 b1 = *(const float4*)(bx + q * 4);
        float4 b2 = *(const float4*)(bh + q * 4);
        float bxx = b1.x + b2.x, byy = b1.y + b2.y;
        float bzz = b1.z + b2.z, bww = b1.w + b2.w;
        r0.x += bxx; r0.y += byy; r0.z += bzz; r0.w += bww;
        r1.x += bxx; r1.y += byy; r1.z += bzz; r1.w += bww;
        r2.x += bxx; r2.y += byy; r2.z += bzz; r2.w += bww;
        r3.x += bxx; r3.y += byy; r3.z += bzz; r3.w += bww;
    }

    // transpose natural -> interleaved via LDS, store bf16
    __syncthreads();
    *(float4*)(sx + (grp * 4 + 0) * 68 + q * 4) = m0;
    *(float4*)(sx + (grp * 4 + 1) * 68 + q * 4) = m1;
    *(float4*)(sx + (grp * 4 + 2) * 68 + q * 4) = m2;
    *(float4*)(sx + (grp * 4 + 3) * 68 + q * 4) = m3;
    __syncthreads();
#pragma unroll
    for (int i = 0; i < 4; ++i) {
        int node = nodeBase + grp * 4 + i;
        if (node < n) {
            const float* rowp = sx + (grp * 4 + i) * 68;
            float a0 = rowp[q], a1 = rowp[16 + q], a2 = rowp[32 + q], a3 = rowp[48 + q];
            ((uint2*)(mxb + (size_t)node * 32))[q] =
                make_uint2(pack_bf16x2(a0, a1), pack_bf16x2(a2, a3));
        }
    }
    if (rootb != nullptr) {
        __syncthreads();
        *(float4*)(sx + (grp * 4 + 0) * 68 + q * 4) = r0;
        *(float4*)(sx + (grp * 4 + 1) * 68 + q * 4) = r1;
        *(float4*)(sx + (grp * 4 + 2) * 68 + q * 4) = r2;
        *(float4*)(sx + (grp * 4 + 3) * 68 + q * 4) = r3;
        __syncthreads();
#pragma unroll
        for (int i = 0; i < 4; ++i) {
            int node = nodeBase + grp * 4 + i;
            if (node < n) {
                const float* rowp = sx + (grp * 4 + i) * 68;
                float a0 = rowp[q], a1 = rowp[16 + q], a2 = rowp[32 + q], a3 = rowp[48 + q];
                ((uint2*)(rootb + (size_t)node * 32))[q] =
                    make_uint2(pack_bf16x2(a0, a1), pack_bf16x2(a2, a3));
            }
        }
    }
}

// ---------------- L2: per-bucket hub (LDS CSR + gather + LSTM) ----------------
__global__ __launch_bounds__(256) void hub_kernel(
        const float* __restrict__ c0, const float* __restrict__ lin_w,
        const float* __restrict__ lin_b,
        const unsigned* __restrict__ mxb, const unsigned* __restrict__ rootb,
        const uint2* __restrict__ pairs, const int* __restrict__ cnts,
        float* __restrict__ out, int n, int epw, int nbktp) {
    __shared__ int deg[NPB], rowptr[NPB], cursor[NPB];
    __shared__ unsigned stage[EMAX];
    __shared__ int csr[EMAX];
    __shared__ int scnt;
    int tid = threadIdx.x;

    // XCD-chunked bucket swizzle (bijective): consecutive buckets -> same XCD.
    int nb = gridDim.x;
    int qq = nb >> 3, rr2 = nb & 7;
    int xcd = blockIdx.x & 7, ix = blockIdx.x >> 3;
    int b = (xcd < rr2) ? xcd * (qq + 1) + ix
                        : rr2 * (qq + 1) + (xcd - rr2) * qq + ix;
    int nstart = b << BSH;

    if (tid < NPB) deg[tid] = 0;
    if (tid == 0) scnt = 0;
    __syncthreads();

    // phase 1: collect this bucket's edges (SEGW=512 segs, 2 per thread)
    int seg0 = tid, seg1 = tid + 256;
    const int* cr0 = cnts + (size_t)seg0 * nbktp;
    const int* cr1 = cnts + (size_t)seg1 * nbktp;
    int o1a = cr0[b], o2a = cr0[b + 1];
    int o1b = cr1[b], o2b = cr1[b + 1];
    int tot = (o2a - o1a) + (o2b - o1b);
    int idx = 0;
    if (tot > 0) idx = atomicAdd(&scnt, tot);
    {
        const uint2* p = pairs + (size_t)seg0 * epw;
        for (int i = o1a; i < o2a; ++i, ++idx) {
            uint2 pr = p[i];
            if (idx < EMAX) {
                int dl = (int)pr.y - nstart;
                stage[idx] = pr.x | ((unsigned)dl << 26);
                atomicAdd(&deg[dl], 1);
            }
        }
        p = pairs + (size_t)seg1 * epw;
        for (int i = o1b; i < o2b; ++i, ++idx) {
            uint2 pr = p[i];
            if (idx < EMAX) {
                int dl = (int)pr.y - nstart;
                stage[idx] = pr.x | ((unsigned)dl << 26);
                atomicAdd(&deg[dl], 1);
            }
        }
    }
    __syncthreads();

    // phase 2: 64-lane wave scan over deg[0..63]
    if (tid < 64) {
        int lane = tid;
        int v = deg[lane];
        int inc = v;
#pragma unroll
        for (int off = 1; off < 64; off <<= 1) {
            int t = __shfl_up(inc, off);
            if (lane >= off) inc += t;
        }
        rowptr[lane] = inc - v;
        cursor[lane] = inc - v;
    }
    __syncthreads();

    // phase 3: place into LDS csr (int LDS atomics — cheap)
    int sc = scnt < EMAX ? scnt : EMAX;
    for (int i = tid; i < sc; i += 256) {
        unsigned v = stage[i];
        int dl = v >> 26;
        int pos = atomicAdd(&cursor[dl], 1);
        csr[pos] = (int)(v & 0x03FFFFFFu);
    }
    __syncthreads();

    // phase 4: gather + LSTM + head.  16 groups x 16 lanes; 4 nodes/group.
    int grp = tid >> 4, q = tid & 15;
    for (int ln = grp; ln < NPB; ln += 16) {
        int node = nstart + ln;
        if (node >= n) continue;
        int cnt = deg[ln];
        const int* row = &csr[rowptr[ln]];

        float ax = 0.f, ay = 0.f, az = 0.f, aw = 0.f;
        int base = 0;
        for (; base + 16 <= cnt; base += 16) {
            int eid = row[base + q];
#pragma unroll
            for (int k = 0; k < 16; ++k) {
                int s = __shfl(eid, k, 16);
                uint2 v = *((const uint2*)(mxb + (size_t)s * 32) + q);
                ax += __uint_as_float(v.x << 16);
                ay += __uint_as_float(v.x & 0xffff0000u);
                az += __uint_as_float(v.y << 16);
                aw += __uint_as_float(v.y & 0xffff0000u);
            }
        }
        int m = cnt - base;
        if (m > 0) {
            int eid = (q < m) ? row[base + q] : 0;
            for (int k = 0; k < m; ++k) {
                int s = __shfl(eid, k, 16);
                uint2 v = *((const uint2*)(mxb + (size_t)s * 32) + q);
                ax += __uint_as_float(v.x << 16);
                ay += __uint_as_float(v.x & 0xffff0000u);
                az += __uint_as_float(v.y << 16);
                aw += __uint_as_float(v.y & 0xffff0000u);
            }
        }

        uint2 rv = *((const uint2*)(rootb + (size_t)node * 32) + q);
        float inv = 1.f / fmaxf((float)cnt, 1.f);
        float px = ax * inv + __uint_as_float(rv.x << 16);
        float py = ay * inv + __uint_as_float(rv.x & 0xffff0000u);
        float pz = az * inv + __uint_as_float(rv.y << 16);
        float pw = aw * inv + __uint_as_float(rv.y & 0xffff0000u);

        float ig = fast_sigmoid(px);
        float fg = fast_sigmoid(py);
        float tg = fast_tanh(pz);
        float og = fast_sigmoid(pw);

        float cn = fg * c0[(size_t)node * NHID + q] + ig * tg;
        float hn = og * fast_tanh(cn);

        out[(size_t)n + (size_t)node * NHID + q] = hn;
        out[(size_t)n + (size_t)n * NHID + (size_t)node * NHID + q] = cn;

        float p = fmaxf(hn, 0.f) * lin_w[q];
#pragma unroll
        for (int off = 8; off; off >>= 1) p += __shfl_xor(p, off, 16);
        if (q == 0) out[node] = p + lin_b[0];
    }
}

// ---------------- fallback path (ws too small) ----------------
__global__ void zero_int_kernel(int4* __restrict__ p, int n4) {
    int i = blockIdx.x * blockDim.x + threadIdx.x;
    if (i < n4) p[i] = make_int4(0, 0, 0, 0);
}
__global__ void scatter_direct_kernel(const int* __restrict__ ei,
                                      int* __restrict__ cursor,
                                      int* __restrict__ csrp, int E, int cap) {
    int e = blockIdx.x * blockDim.x + threadIdx.x;
    if (e < E) {
        int d = ei[E + e];
        int pos = atomicAdd(&cursor[d], 1);
        if (pos < cap) csrp[(size_t)d * cap + pos] = ei[e];
    }
}
__global__ __launch_bounds__(256) void gfinal_inl(
        const float* __restrict__ x, const float* __restrict__ h0,
        const float* __restrict__ c0,
        const float* __restrict__ Rx, const float* __restrict__ Rh,
        const float* __restrict__ bx, const float* __restrict__ bh,
        const float* __restrict__ lin_w, const float* __restrict__ lin_b,
        const unsigned* __restrict__ mxb, const int* __restrict__ csrp,
        const int* __restrict__ cursor,
        float* __restrict__ out, int n, int cap) {
    __shared__ float sm[16 * 68];
    int idx = blockIdx.x * 256 + threadIdx.x;
    int node = idx >> 4, q = idx & 15;
    int nl = threadIdx.x >> 4;
    bool valid = node < n;

    int cnt = 0;
    if (valid) cnt = cursor[node];
    int mt = cnt < cap ? cnt : cap;
    const int* row = csrp + (size_t)node * cap;

    float ax = 0.f, ay = 0.f, az = 0.f, aw = 0.f;
    int base = 0;
    for (; base + 16 <= mt; base += 16) {
        int eid = row[base + q];
#pragma unroll
        for (int k = 0; k < 16; ++k) {
            int s = __shfl(eid, k, 16);
            uint2 v = *((const uint2*)(mxb + (size_t)s * 32) + q);
            ax += __uint_as_float(v.x << 16);
            ay += __uint_as_float(v.x & 0xffff0000u);
            az += __uint_as_float(v.y << 16);
            aw += __uint_as_float(v.y & 0xffff0000u);
        }
    }
    int mrem = mt - base;
    if (mrem > 0) {
        int eid = (q < mrem) ? row[base + q] : 0;
        for (int k = 0; k < mrem; ++k) {
            int s = __shfl(eid, k, 16);
            uint2 v = *((const uint2*)(mxb + (size_t)s * 32) + q);
            ax += __uint_as_float(v.x << 16);
            ay += __uint_as_float(v.x & 0xffff0000u);
            az += __uint_as_float(v.y << 16);
            aw += __uint_as_float(v.y & 0xffff0000u);
        }
    }

    float4 r = make_float4(0.f, 0.f, 0.f, 0.f);
    if (valid) {
        int g = q >> 2, rr = q & 3;
        const float* xr = x + (size_t)node * F_IN;
        const float* hr = h0 + (size_t)node * NHID;
        const float* rx = Rx + g * (F_IN * NHID) + rr * 4;
        const float* rh = Rh + g * (NHID * NHID) + rr * 4;
#pragma unroll 8
        for (int k = 0; k < F_IN; ++k) fma4(r, xr[k], *(const float4*)(rx + k * NHID));
#pragma unroll
        for (int k = 0; k < NHID; ++k) fma4(r, hr[k], *(const float4*)(rh + k * NHID));
        float4 b1 = *(const float4*)(bx + q * 4);
        float4 b2 = *(const float4*)(bh + q * 4);
        r.x += b1.x + b2.x; r.y += b1.y + b2.y;
        r.z += b1.z + b2.z; r.w += b1.w + b2.w;
    }
    *(float4*)(sm + nl * 68 + q * 4) = r;
    __syncthreads();

    if (valid) {
        const float* rowp = sm + nl * 68;
        float inv = 1.f / fmaxf((float)cnt, 1.f);
        float px = ax * inv + rowp[q];
        float py = ay * inv + rowp[16 + q];
        float pz = az * inv + rowp[32 + q];
        float pw = aw * inv + rowp[48 + q];
        float ig = fast_sigmoid(px);
        float fg = fast_sigmoid(py);
        float tg = fast_tanh(pz);
        float og = fast_sigmoid(pw);
        float cn = fg * c0[(size_t)node * NHID + q] + ig * tg;
        float hn = og * fast_tanh(cn);
        out[(size_t)n + (size_t)node * NHID + q] = hn;
        out[(size_t)n + (size_t)n * NHID + (size_t)node * NHID + q] = cn;
        float p = fmaxf(hn, 0.f) * lin_w[q];
#pragma unroll
        for (int off = 8; off; off >>= 1) p += __shfl_xor(p, off, 16);
        if (q == 0) out[node] = p + lin_b[0];
    }
}

extern "C" void kernel_launch(void* const* d_in, const int* in_sizes, int n_in,
                              void* d_out, int out_size, void* d_ws, size_t ws_size,
                              hipStream_t stream) {
    const float* x     = (const float*)d_in[0];
    const int*   ei    = (const int*)d_in[1];
    const float* h0    = (const float*)d_in[3];
    const float* c0    = (const float*)d_in[4];
    const float* Wx    = (const float*)d_in[5];
    const float* Rx    = (const float*)d_in[6];
    const float* bx    = (const float*)d_in[7];
    const float* Wh    = (const float*)d_in[8];
    const float* Rh    = (const float*)d_in[9];
    const float* bh    = (const float*)d_in[10];
    const float* lin_w = (const float*)d_in[11];
    const float* lin_b = (const float*)d_in[12];

    const int N = in_sizes[3] / NHID;
    const int E = in_sizes[1] / 2;
    const int NBKT  = (N + NPB - 1) >> BSH;           // 1563 for N=100000
    const int nbktp = ((NBKT + 1) + 15) & ~15;        // 1568
    const int epw   = ((E + SEGW - 1) / SEGW + 7) & ~7;

    // u32 units
    const size_t mxb_u   = (size_t)N * 32;
    const size_t root_u  = (size_t)N * 32;
    const size_t pairs_u = 2ull * SEGW * epw;
    const size_t cnts_u  = (size_t)SEGW * nbktp;
    const size_t need = (mxb_u + root_u + pairs_u + cnts_u) * 4;

    unsigned* wsu = (unsigned*)d_ws;
    float* out = (float*)d_out;
    const int projBlocks = (N + 31) / 32;

    // dynamic LDS for fused kernel: max(partw 2*nbktp*4, proj 32*68*4+32*20*4)
    size_t ldsPart = (size_t)2 * nbktp * sizeof(int);
    size_t ldsProj = (32 * 68 + 32 * 20) * sizeof(float);
    size_t ldsFused = ldsPart > ldsProj ? ldsPart : ldsProj;

    if (ws_size >= need) {
        unsigned* mxb   = wsu;
        unsigned* rootb = mxb + mxb_u;
        uint2*    pairs = (uint2*)(rootb + root_u);
        int*      cnts  = (int*)(pairs + (size_t)SEGW * epw);

        fused_pp2<<<PARTB + projBlocks, 128, (int)ldsFused, stream>>>(
            ei, pairs, cnts, E, epw, NBKT, nbktp,
            x, h0, Wx, Wh, Rx, Rh, bx, bh, mxb, rootb, N, PARTB);
        hub_kernel<<<NBKT, 256, 0, stream>>>(
            c0, lin_w, lin_b, mxb, rootb, pairs, cnts, out, N, epw, nbktp);
    } else {
        const int cap = 32;
        const int P = (N + 3) & ~3;
        unsigned* mxb   = wsu;
        int*      cursor= (int*)(mxb + mxb_u);
        int*      csrp  = cursor + P;

        zero_int_kernel<<<(P / 4 + 255) / 256, 256, 0, stream>>>((int4*)cursor, P / 4);
        fused_pp2<<<projBlocks, 128, (int)ldsProj, stream>>>(
            ei, nullptr, nullptr, E, epw, NBKT, nbktp,
            x, h0, Wx, Wh, Rx, Rh, bx, bh, mxb, nullptr, N, 0);
        scatter_direct_kernel<<<(E + 255) / 256, 256, 0, stream>>>(
            ei, cursor, csrp, E, cap);
        gfinal_inl<<<(N * 16 + 255) / 256, 256, 0, stream>>>(
            x, h0, c0, Rx, Rh, bx, bh, lin_w, lin_b, mxb, csrp, cursor,
            out, N, cap);
    }
}

// Round 18
// 117.405 us; speedup vs baseline: 1.2058x; 1.1953x over previous
//
#include <hip/hip_runtime.h>

// LRGCN cell on MI355X — 2-launch design:
//   L1 fused : [partw role, blocks 0..127: 4 waves, 1 seg/wave, LDS hist+scan,
//               bucket (src,dst) by dst>>6 into wave-private pair regions]  ∥
//              [proj role: 64 nodes/block; r18: ALL WEIGHTS STAGED IN LDS —
//               r17 showed the compiler re-rolls register pipelines (VGPR=40)
//               so the 40KB weight set (L1 is 32KB) exposes serial L2 latency
//               every iteration; LDS reads are ~12cy pipelined].
//   L2 hub   : one block per 64-node bucket, XCD-chunked swizzle, 64-lane
//              wave scan: collect pairs -> LDS deg/rowptr/csr (int LDS
//              atomics; f32 LDS atomics ~7x slower, r13) -> shfl-gather
//              mxb -> LSTM -> out.
//
// Interleaved layout: stored[4j+t] = natural[16t+j]  (j=hidden unit, t=gate).
// mean_agg(x)@W == mean_agg(x@W) (linearity) makes pre-projection valid.
//
// Inputs: 0 x[N,64] f32 | 1 ei[2,E] i32 | 2 ew[E] (unused) | 3 h0[N,16]
// | 4 c0[N,16] | 5 Wx[4,64,16] | 6 Rx | 7 bx[4,16] | 8 Wh[4,16,16] | 9 Rh
// | 10 bh | 11 lin_w[16] | 12 lin_b[1]
// Output: concat( out[N], h_new[N*16], c_new[N*16] ) f32

#define F_IN 64
#define NHID 16
#define BSH  6               // bucket shift: 64 nodes/bucket
#define NPB  64              // nodes per bucket
#define SEGW 512             // partition wave-segments
#define PARTB (SEGW / 4)     // partw-role blocks (4 waves, 1 seg each)
#define EMAX 1280            // per-bucket edge capacity (mean ~1024, +8 sigma)

// LDS float offsets for proj role (padded gate strides: 1032 mod 32 = 8,
// 264 mod 32 = 8 -> 16 lanes' b128 reads land 2-way per bank = free)
#define LWX 0
#define LRX 4128
#define LWH 8256
#define LRH 9312
#define LSX 10368            // 64 rows x 68
#define LSH 14720            // 64 rows x 20
#define LDSF 16000           // total floats (64000 B)

__device__ __forceinline__ unsigned pack_bf16x2(float lo, float hi) {
    unsigned a = __float_as_uint(lo);
    unsigned b = __float_as_uint(hi);
    a = (a + 0x7fffu + ((a >> 16) & 1u)) >> 16;
    b = (b + 0x7fffu + ((b >> 16) & 1u)) >> 16;
    return a | (b << 16);
}
__device__ __forceinline__ float fast_sigmoid(float v) {
    return 1.f / (1.f + __expf(-v));
}
__device__ __forceinline__ float fast_tanh(float v) {
    return 1.f - 2.f / (1.f + __expf(2.f * v));
}
__device__ __forceinline__ void fma4(float4& a, float s, const float4& wv) {
    a.x += s * wv.x; a.y += s * wv.y; a.z += s * wv.z; a.w += s * wv.w;
}

// ---------------- L1: fused [partw | proj], 256 threads ----------------
__global__ __launch_bounds__(256) void fused_pp2(
        const int* __restrict__ ei, uint2* __restrict__ pairs,
        int* __restrict__ cnts, int E, int epw, int nbkt, int nbktp,
        const float* __restrict__ x, const float* __restrict__ h0,
        const float* __restrict__ Wx, const float* __restrict__ Wh,
        const float* __restrict__ Rx, const float* __restrict__ Rh,
        const float* __restrict__ bx, const float* __restrict__ bh,
        unsigned* __restrict__ mxb, unsigned* __restrict__ rootb,
        int n, int partBlocks) {
    extern __shared__ float smem[];
    int tid = threadIdx.x;

    if ((int)blockIdx.x < partBlocks) {
        // ======== partw role: 4 waves, one segment each ========
        int* cnt_s = (int*)smem;
        int wv = tid >> 6, lane = tid & 63;
        int seg = blockIdx.x * 4 + wv;
        int* cnt = cnt_s + wv * nbktp;

        for (int i = lane; i < nbktp; i += 64) cnt[i] = 0;
        __syncthreads();

        int beg = seg * epw;
        int end = beg + epw; if (end > E) end = E;

        // pass 1: histogram by bucket
        for (int e = beg + lane; e < end; e += 64)
            atomicAdd(&cnt[((unsigned)ei[E + e]) >> BSH], 1);
        __syncthreads();

        // wave-exclusive scan over cnt[0..nbkt), total at cnt[nbkt]
        int per = (nbkt + 63) >> 6;
        int s0 = lane * per;
        int s1 = s0 + per; if (s1 > nbkt) s1 = nbkt;
        if (s0 > nbkt) s0 = nbkt;
        int sum = 0;
        for (int i = s0; i < s1; ++i) sum += cnt[i];
        int inc = sum;
#pragma unroll
        for (int off = 1; off < 64; off <<= 1) {
            int v = __shfl_up(inc, off);
            if (lane >= off) inc += v;
        }
        int run = inc - sum;
        for (int i = s0; i < s1; ++i) { int c = cnt[i]; cnt[i] = run; run += c; }
        if (lane == 63) cnt[nbkt] = run;
        __syncthreads();

        // publish offsets (coalesced)
        for (int i = lane; i <= nbkt; i += 64)
            cnts[(size_t)seg * nbktp + i] = cnt[i];

        // pass 2: placement into wave-private region (cnt[] now cursors)
        uint2* wreg = pairs + (size_t)seg * epw;
        for (int e = beg + lane; e < end; e += 64) {
            unsigned s = (unsigned)ei[e];
            unsigned d = (unsigned)ei[E + e];
            int pos = atomicAdd(&cnt[d >> BSH], 1);
            wreg[pos] = make_uint2(s, d);
        }
        return;
    }

    // ======== proj role: 64 nodes/block, weights in LDS ========
    float* lwx = smem + LWX;
    float* lrx = smem + LRX;
    float* lwh = smem + LWH;
    float* lrh = smem + LRH;
    float* sx  = smem + LSX;
    float* sh  = smem + LSH;
    int nodeBase = ((int)blockIdx.x - partBlocks) * 64;

    // stage weights (coalesced, padded gate strides)
#pragma unroll
    for (int i = 0; i < 4; ++i) {
        int idx = i * 256 + tid;           // float4 index 0..1023
        int gg = idx >> 8;
        int off = (idx & 255) * 4;
        *(float4*)(lwx + gg * 1032 + off) = ((const float4*)Wx)[idx];
        *(float4*)(lrx + gg * 1032 + off) = ((const float4*)Rx)[idx];
    }
    {
        int idx = tid;                     // float4 index 0..255
        int gg = idx >> 6;
        int off = (idx & 63) * 4;
        *(float4*)(lwh + gg * 264 + off) = ((const float4*)Wh)[idx];
        *(float4*)(lrh + gg * 264 + off) = ((const float4*)Rh)[idx];
    }
    // stage x (64 rows x 16 float4) and h (64 rows x 4 float4)
#pragma unroll
    for (int i = 0; i < 4; ++i) {
        int idx = i * 256 + tid;
        int row = idx >> 4, c4 = idx & 15;
        int node = nodeBase + row;
        float4 v = make_float4(0.f, 0.f, 0.f, 0.f);
        if (node < n) v = ((const float4*)(x + (size_t)node * F_IN))[c4];
        *(float4*)(sx + row * 68 + c4 * 4) = v;
    }
    {
        int row = tid >> 2, c4 = tid & 3;
        int node = nodeBase + row;
        float4 v = make_float4(0.f, 0.f, 0.f, 0.f);
        if (node < n) v = ((const float4*)(h0 + (size_t)node * NHID))[c4];
        *(float4*)(sh + row * 20 + c4 * 4) = v;
    }
    __syncthreads();

    int grp = tid >> 4, q = tid & 15;      // grp 0..15, 4 nodes each
    int g = q >> 2, rr = q & 3;
    const float* wxp = lwx + g * 1032 + rr * 4;
    const float* rxp = lrx + g * 1032 + rr * 4;
    const float* whp = lwh + g * 264 + rr * 4;
    const float* rhp = lrh + g * 264 + rr * 4;
    const float* sx0 = sx + (grp * 4 + 0) * 68;
    const float* sx1 = sx + (grp * 4 + 1) * 68;
    const float* sx2 = sx + (grp * 4 + 2) * 68;
    const float* sx3 = sx + (grp * 4 + 3) * 68;
    const float* sh0 = sh + (grp * 4 + 0) * 20;
    const float* sh1 = sh + (grp * 4 + 1) * 20;
    const float* sh2 = sh + (grp * 4 + 2) * 20;
    const float* sh3 = sh + (grp * 4 + 3) * 20;

    float4 m0 = make_float4(0.f, 0.f, 0.f, 0.f), m1 = m0, m2 = m0, m3 = m0;
    float4 r0 = m0, r1 = m0, r2 = m0, r3 = m0;

#pragma unroll 1
    for (int k = 0; k < F_IN; k += 4) {
        float4 xa = *(const float4*)(sx0 + k);
        float4 xb = *(const float4*)(sx1 + k);
        float4 xc = *(const float4*)(sx2 + k);
        float4 xd = *(const float4*)(sx3 + k);
        float4 w0 = *(const float4*)(wxp + (k + 0) * NHID);
        float4 w1 = *(const float4*)(wxp + (k + 1) * NHID);
        float4 w2 = *(const float4*)(wxp + (k + 2) * NHID);
        float4 w3 = *(const float4*)(wxp + (k + 3) * NHID);
        float4 v0 = *(const float4*)(rxp + (k + 0) * NHID);
        float4 v1 = *(const float4*)(rxp + (k + 1) * NHID);
        float4 v2 = *(const float4*)(rxp + (k + 2) * NHID);
        float4 v3 = *(const float4*)(rxp + (k + 3) * NHID);
        fma4(m0, xa.x, w0); fma4(m0, xa.y, w1); fma4(m0, xa.z, w2); fma4(m0, xa.w, w3);
        fma4(m1, xb.x, w0); fma4(m1, xb.y, w1); fma4(m1, xb.z, w2); fma4(m1, xb.w, w3);
        fma4(m2, xc.x, w0); fma4(m2, xc.y, w1); fma4(m2, xc.z, w2); fma4(m2, xc.w, w3);
        fma4(m3, xd.x, w0); fma4(m3, xd.y, w1); fma4(m3, xd.z, w2); fma4(m3, xd.w, w3);
        fma4(r0, xa.x, v0); fma4(r0, xa.y, v1); fma4(r0, xa.z, v2); fma4(r0, xa.w, v3);
        fma4(r1, xb.x, v0); fma4(r1, xb.y, v1); fma4(r1, xb.z, v2); fma4(r1, xb.w, v3);
        fma4(r2, xc.x, v0); fma4(r2, xc.y, v1); fma4(r2, xc.z, v2); fma4(r2, xc.w, v3);
        fma4(r3, xd.x, v0); fma4(r3, xd.y, v1); fma4(r3, xd.z, v2); fma4(r3, xd.w, v3);
    }
#pragma unroll 1
    for (int k = 0; k < NHID; k += 4) {
        float4 xa = *(const float4*)(sh0 + k);
        float4 xb = *(const float4*)(sh1 + k);
        float4 xc = *(const float4*)(sh2 + k);
        float4 xd = *(const float4*)(sh3 + k);
        float4 w0 = *(const float4*)(whp + (k + 0) * NHID);
        float4 w1 = *(const float4*)(whp + (k + 1) * NHID);
        float4 w2 = *(const float4*)(whp + (k + 2) * NHID);
        float4 w3 = *(const float4*)(whp + (k + 3) * NHID);
        float4 v0 = *(const float4*)(rhp + (k + 0) * NHID);
        float4 v1 = *(const float4*)(rhp + (k + 1) * NHID);
        float4 v2 = *(const float4*)(rhp + (k + 2) * NHID);
        float4 v3 = *(const float4*)(rhp + (k + 3) * NHID);
        fma4(m0, xa.x, w0); fma4(m0, xa.y, w1); fma4(m0, xa.z, w2); fma4(m0, xa.w, w3);
        fma4(m1, xb.x, w0); fma4(m1, xb.y, w1); fma4(m1, xb.z, w2); fma4(m1, xb.w, w3);
        fma4(m2, xc.x, w0); fma4(m2, xc.y, w1); fma4(m2, xc.z, w2); fma4(m2, xc.w, w3);
        fma4(m3, xd.x, w0); fma4(m3, xd.y, w1); fma4(m3, xd.z, w2); fma4(m3, xd.w, w3);
        fma4(r0, xa.x, v0); fma4(r0, xa.y, v1); fma4(r0, xa.z, v2); fma4(r0, xa.w, v3);
        fma4(r1, xb.x, v0); fma4(r1, xb.y, v1); fma4(r1, xb.z, v2); fma4(r1, xb.w, v3);
        fma4(r2, xc.x, v0); fma4(r2, xc.y, v1); fma4(r2, xc.z, v2); fma4(r2, xc.w, v3);
        fma4(r3, xd.x, v0); fma4(r3, xd.y, v1); fma4(r3, xd.z, v2); fma4(r3, xd.w, v3);
    }
    {   // biases into root (natural cols 4q..4q+3)
        float4 b1 = *(const float4*)(bx + q * 4);
        float4 b2 = *(const float4*)(bh + q * 4);
        float bxx = b1.x + b2.x, byy = b1.y + b2.y;
        float bzz = b1.z + b2.z, bww = b1.w + b2.w;
        r0.x += bxx; r0.y += byy; r0.z += bzz; r0.w += bww;
        r1.x += bxx; r1.y += byy; r1.z += bzz; r1.w += bww;
        r2.x += bxx; r2.y += byy; r2.z += bzz; r2.w += bww;
        r3.x += bxx; r3.y += byy; r3.z += bzz; r3.w += bww;
    }

    // transpose natural -> interleaved via LDS (reuse sx), store bf16
    __syncthreads();
    *(float4*)(sx + (grp * 4 + 0) * 68 + q * 4) = m0;
    *(float4*)(sx + (grp * 4 + 1) * 68 + q * 4) = m1;
    *(float4*)(sx + (grp * 4 + 2) * 68 + q * 4) = m2;
    *(float4*)(sx + (grp * 4 + 3) * 68 + q * 4) = m3;
    __syncthreads();
#pragma unroll
    for (int i = 0; i < 4; ++i) {
        int node = nodeBase + grp * 4 + i;
        if (node < n) {
            const float* rowp = sx + (grp * 4 + i) * 68;
            float a0 = rowp[q], a1 = rowp[16 + q], a2 = rowp[32 + q], a3 = rowp[48 + q];
            ((uint2*)(mxb + (size_t)node * 32))[q] =
                make_uint2(pack_bf16x2(a0, a1), pack_bf16x2(a2, a3));
        }
    }
    if (rootb != nullptr) {
        __syncthreads();
        *(float4*)(sx + (grp * 4 + 0) * 68 + q * 4) = r0;
        *(float4*)(sx + (grp * 4 + 1) * 68 + q * 4) = r1;
        *(float4*)(sx + (grp * 4 + 2) * 68 + q * 4) = r2;
        *(float4*)(sx + (grp * 4 + 3) * 68 + q * 4) = r3;
        __syncthreads();
#pragma unroll
        for (int i = 0; i < 4; ++i) {
            int node = nodeBase + grp * 4 + i;
            if (node < n) {
                const float* rowp = sx + (grp * 4 + i) * 68;
                float a0 = rowp[q], a1 = rowp[16 + q], a2 = rowp[32 + q], a3 = rowp[48 + q];
                ((uint2*)(rootb + (size_t)node * 32))[q] =
                    make_uint2(pack_bf16x2(a0, a1), pack_bf16x2(a2, a3));
            }
        }
    }
}

// ---------------- L2: per-bucket hub (LDS CSR + gather + LSTM) ----------------
__global__ __launch_bounds__(256) void hub_kernel(
        const float* __restrict__ c0, const float* __restrict__ lin_w,
        const float* __restrict__ lin_b,
        const unsigned* __restrict__ mxb, const unsigned* __restrict__ rootb,
        const uint2* __restrict__ pairs, const int* __restrict__ cnts,
        float* __restrict__ out, int n, int epw, int nbktp) {
    __shared__ int deg[NPB], rowptr[NPB], cursor[NPB];
    __shared__ unsigned stage[EMAX];
    __shared__ int csr[EMAX];
    __shared__ int scnt;
    int tid = threadIdx.x;

    // XCD-chunked bucket swizzle (bijective): consecutive buckets -> same XCD.
    int nb = gridDim.x;
    int qq = nb >> 3, rr2 = nb & 7;
    int xcd = blockIdx.x & 7, ix = blockIdx.x >> 3;
    int b = (xcd < rr2) ? xcd * (qq + 1) + ix
                        : rr2 * (qq + 1) + (xcd - rr2) * qq + ix;
    int nstart = b << BSH;

    if (tid < NPB) deg[tid] = 0;
    if (tid == 0) scnt = 0;
    __syncthreads();

    // phase 1: collect this bucket's edges (SEGW=512 segs, 2 per thread)
    int seg0 = tid, seg1 = tid + 256;
    const int* cr0 = cnts + (size_t)seg0 * nbktp;
    const int* cr1 = cnts + (size_t)seg1 * nbktp;
    int o1a = cr0[b], o2a = cr0[b + 1];
    int o1b = cr1[b], o2b = cr1[b + 1];
    int tot = (o2a - o1a) + (o2b - o1b);
    int idx = 0;
    if (tot > 0) idx = atomicAdd(&scnt, tot);
    {
        const uint2* p = pairs + (size_t)seg0 * epw;
        for (int i = o1a; i < o2a; ++i, ++idx) {
            uint2 pr = p[i];
            if (idx < EMAX) {
                int dl = (int)pr.y - nstart;
                stage[idx] = pr.x | ((unsigned)dl << 26);
                atomicAdd(&deg[dl], 1);
            }
        }
        p = pairs + (size_t)seg1 * epw;
        for (int i = o1b; i < o2b; ++i, ++idx) {
            uint2 pr = p[i];
            if (idx < EMAX) {
                int dl = (int)pr.y - nstart;
                stage[idx] = pr.x | ((unsigned)dl << 26);
                atomicAdd(&deg[dl], 1);
            }
        }
    }
    __syncthreads();

    // phase 2: 64-lane wave scan over deg[0..63]
    if (tid < 64) {
        int lane = tid;
        int v = deg[lane];
        int inc = v;
#pragma unroll
        for (int off = 1; off < 64; off <<= 1) {
            int t = __shfl_up(inc, off);
            if (lane >= off) inc += t;
        }
        rowptr[lane] = inc - v;
        cursor[lane] = inc - v;
    }
    __syncthreads();

    // phase 3: place into LDS csr (int LDS atomics — cheap)
    int sc = scnt < EMAX ? scnt : EMAX;
    for (int i = tid; i < sc; i += 256) {
        unsigned v = stage[i];
        int dl = v >> 26;
        int pos = atomicAdd(&cursor[dl], 1);
        csr[pos] = (int)(v & 0x03FFFFFFu);
    }
    __syncthreads();

    // phase 4: gather + LSTM + head.  16 groups x 16 lanes; 4 nodes/group.
    int grp = tid >> 4, q = tid & 15;
    for (int ln = grp; ln < NPB; ln += 16) {
        int node = nstart + ln;
        if (node >= n) continue;
        int cnt = deg[ln];
        const int* row = &csr[rowptr[ln]];

        float ax = 0.f, ay = 0.f, az = 0.f, aw = 0.f;
        int base = 0;
        for (; base + 16 <= cnt; base += 16) {
            int eid = row[base + q];
#pragma unroll
            for (int k = 0; k < 16; ++k) {
                int s = __shfl(eid, k, 16);
                uint2 v = *((const uint2*)(mxb + (size_t)s * 32) + q);
                ax += __uint_as_float(v.x << 16);
                ay += __uint_as_float(v.x & 0xffff0000u);
                az += __uint_as_float(v.y << 16);
                aw += __uint_as_float(v.y & 0xffff0000u);
            }
        }
        int m = cnt - base;
        if (m > 0) {
            int eid = (q < m) ? row[base + q] : 0;
            for (int k = 0; k < m; ++k) {
                int s = __shfl(eid, k, 16);
                uint2 v = *((const uint2*)(mxb + (size_t)s * 32) + q);
                ax += __uint_as_float(v.x << 16);
                ay += __uint_as_float(v.x & 0xffff0000u);
                az += __uint_as_float(v.y << 16);
                aw += __uint_as_float(v.y & 0xffff0000u);
            }
        }

        uint2 rv = *((const uint2*)(rootb + (size_t)node * 32) + q);
        float inv = 1.f / fmaxf((float)cnt, 1.f);
        float px = ax * inv + __uint_as_float(rv.x << 16);
        float py = ay * inv + __uint_as_float(rv.x & 0xffff0000u);
        float pz = az * inv + __uint_as_float(rv.y << 16);
        float pw = aw * inv + __uint_as_float(rv.y & 0xffff0000u);

        float ig = fast_sigmoid(px);
        float fg = fast_sigmoid(py);
        float tg = fast_tanh(pz);
        float og = fast_sigmoid(pw);

        float cn = fg * c0[(size_t)node * NHID + q] + ig * tg;
        float hn = og * fast_tanh(cn);

        out[(size_t)n + (size_t)node * NHID + q] = hn;
        out[(size_t)n + (size_t)n * NHID + (size_t)node * NHID + q] = cn;

        float p = fmaxf(hn, 0.f) * lin_w[q];
#pragma unroll
        for (int off = 8; off; off >>= 1) p += __shfl_xor(p, off, 16);
        if (q == 0) out[node] = p + lin_b[0];
    }
}

// ---------------- fallback path (ws too small) ----------------
__global__ void zero_int_kernel(int4* __restrict__ p, int n4) {
    int i = blockIdx.x * blockDim.x + threadIdx.x;
    if (i < n4) p[i] = make_int4(0, 0, 0, 0);
}
__global__ void scatter_direct_kernel(const int* __restrict__ ei,
                                      int* __restrict__ cursor,
                                      int* __restrict__ csrp, int E, int cap) {
    int e = blockIdx.x * blockDim.x + threadIdx.x;
    if (e < E) {
        int d = ei[E + e];
        int pos = atomicAdd(&cursor[d], 1);
        if (pos < cap) csrp[(size_t)d * cap + pos] = ei[e];
    }
}
__global__ __launch_bounds__(256) void gfinal_inl(
        const float* __restrict__ x, const float* __restrict__ h0,
        const float* __restrict__ c0,
        const float* __restrict__ Rx, const float* __restrict__ Rh,
        const float* __restrict__ bx, const float* __restrict__ bh,
        const float* __restrict__ lin_w, const float* __restrict__ lin_b,
        const unsigned* __restrict__ mxb, const int* __restrict__ csrp,
        const int* __restrict__ cursor,
        float* __restrict__ out, int n, int cap) {
    __shared__ float sm[16 * 68];
    int idx = blockIdx.x * 256 + threadIdx.x;
    int node = idx >> 4, q = idx & 15;
    int nl = threadIdx.x >> 4;
    bool valid = node < n;

    int cnt = 0;
    if (valid) cnt = cursor[node];
    int mt = cnt < cap ? cnt : cap;
    const int* row = csrp + (size_t)node * cap;

    float ax = 0.f, ay = 0.f, az = 0.f, aw = 0.f;
    int base = 0;
    for (; base + 16 <= mt; base += 16) {
        int eid = row[base + q];
#pragma unroll
        for (int k = 0; k < 16; ++k) {
            int s = __shfl(eid, k, 16);
            uint2 v = *((const uint2*)(mxb + (size_t)s * 32) + q);
            ax += __uint_as_float(v.x << 16);
            ay += __uint_as_float(v.x & 0xffff0000u);
            az += __uint_as_float(v.y << 16);
            aw += __uint_as_float(v.y & 0xffff0000u);
        }
    }
    int mrem = mt - base;
    if (mrem > 0) {
        int eid = (q < mrem) ? row[base + q] : 0;
        for (int k = 0; k < mrem; ++k) {
            int s = __shfl(eid, k, 16);
            uint2 v = *((const uint2*)(mxb + (size_t)s * 32) + q);
            ax += __uint_as_float(v.x << 16);
            ay += __uint_as_float(v.x & 0xffff0000u);
            az += __uint_as_float(v.y << 16);
            aw += __uint_as_float(v.y & 0xffff0000u);
        }
    }

    float4 r = make_float4(0.f, 0.f, 0.f, 0.f);
    if (valid) {
        int g = q >> 2, rr = q & 3;
        const float* xr = x + (size_t)node * F_IN;
        const float* hr = h0 + (size_t)node * NHID;
        const float* rx = Rx + g * (F_IN * NHID) + rr * 4;
        const float* rh = Rh + g * (NHID * NHID) + rr * 4;
#pragma unroll 8
        for (int k = 0; k < F_IN; ++k) fma4(r, xr[k], *(const float4*)(rx + k * NHID));
#pragma unroll
        for (int k = 0; k < NHID; ++k) fma4(r, hr[k], *(const float4*)(rh + k * NHID));
        float4 b1 = *(const float4*)(bx + q * 4);
        float4 b2 = *(const float4*)(bh + q * 4);
        r.x += b1.x + b2.x; r.y += b1.y + b2.y;
        r.z += b1.z + b2.z; r.w += b1.w + b2.w;
    }
    *(float4*)(sm + nl * 68 + q * 4) = r;
    __syncthreads();

    if (valid) {
        const float* rowp = sm + nl * 68;
        float inv = 1.f / fmaxf((float)cnt, 1.f);
        float px = ax * inv + rowp[q];
        float py = ay * inv + rowp[16 + q];
        float pz = az * inv + rowp[32 + q];
        float pw = aw * inv + rowp[48 + q];
        float ig = fast_sigmoid(px);
        float fg = fast_sigmoid(py);
        float tg = fast_tanh(pz);
        float og = fast_sigmoid(pw);
        float cn = fg * c0[(size_t)node * NHID + q] + ig * tg;
        float hn = og * fast_tanh(cn);
        out[(size_t)n + (size_t)node * NHID + q] = hn;
        out[(size_t)n + (size_t)n * NHID + (size_t)node * NHID + q] = cn;
        float p = fmaxf(hn, 0.f) * lin_w[q];
#pragma unroll
        for (int off = 8; off; off >>= 1) p += __shfl_xor(p, off, 16);
        if (q == 0) out[node] = p + lin_b[0];
    }
}

extern "C" void kernel_launch(void* const* d_in, const int* in_sizes, int n_in,
                              void* d_out, int out_size, void* d_ws, size_t ws_size,
                              hipStream_t stream) {
    const float* x     = (const float*)d_in[0];
    const int*   ei    = (const int*)d_in[1];
    const float* h0    = (const float*)d_in[3];
    const float* c0    = (const float*)d_in[4];
    const float* Wx    = (const float*)d_in[5];
    const float* Rx    = (const float*)d_in[6];
    const float* bx    = (const float*)d_in[7];
    const float* Wh    = (const float*)d_in[8];
    const float* Rh    = (const float*)d_in[9];
    const float* bh    = (const float*)d_in[10];
    const float* lin_w = (const float*)d_in[11];
    const float* lin_b = (const float*)d_in[12];

    const int N = in_sizes[3] / NHID;
    const int E = in_sizes[1] / 2;
    const int NBKT  = (N + NPB - 1) >> BSH;           // 1563 for N=100000
    const int nbktp = ((NBKT + 1) + 15) & ~15;        // 1568
    const int epw   = ((E + SEGW - 1) / SEGW + 7) & ~7;

    // u32 units
    const size_t mxb_u   = (size_t)N * 32;
    const size_t root_u  = (size_t)N * 32;
    const size_t pairs_u = 2ull * SEGW * epw;
    const size_t cnts_u  = (size_t)SEGW * nbktp;
    const size_t need = (mxb_u + root_u + pairs_u + cnts_u) * 4;

    unsigned* wsu = (unsigned*)d_ws;
    float* out = (float*)d_out;
    const int projBlocks = (N + 63) / 64;

    // dynamic LDS: max(partw 4*nbktp*4 = 25KB, proj LDSF*4 = 64000 B)
    size_t ldsPart = (size_t)4 * nbktp * sizeof(int);
    size_t ldsProj = (size_t)LDSF * sizeof(float);
    size_t ldsFused = ldsPart > ldsProj ? ldsPart : ldsProj;

    if (ws_size >= need) {
        unsigned* mxb   = wsu;
        unsigned* rootb = mxb + mxb_u;
        uint2*    pairs = (uint2*)(rootb + root_u);
        int*      cnts  = (int*)(pairs + (size_t)SEGW * epw);

        fused_pp2<<<PARTB + projBlocks, 256, (int)ldsFused, stream>>>(
            ei, pairs, cnts, E, epw, NBKT, nbktp,
            x, h0, Wx, Wh, Rx, Rh, bx, bh, mxb, rootb, N, PARTB);
        hub_kernel<<<NBKT, 256, 0, stream>>>(
            c0, lin_w, lin_b, mxb, rootb, pairs, cnts, out, N, epw, nbktp);
    } else {
        const int cap = 32;
        const int P = (N + 3) & ~3;
        unsigned* mxb   = wsu;
        int*      cursor= (int*)(mxb + mxb_u);
        int*      csrp  = cursor + P;

        zero_int_kernel<<<(P / 4 + 255) / 256, 256, 0, stream>>>((int4*)cursor, P / 4);
        fused_pp2<<<projBlocks, 256, (int)ldsProj, stream>>>(
            ei, nullptr, nullptr, E, epw, NBKT, nbktp,
            x, h0, Wx, Wh, Rx, Rh, bx, bh, mxb, nullptr, N, 0);
        scatter_direct_kernel<<<(E + 255) / 256, 256, 0, stream>>>(
            ei, cursor, csrp, E, cap);
        gfinal_inl<<<(N * 16 + 255) / 256, 256, 0, stream>>>(
            x, h0, c0, Rx, Rh, bx, bh, lin_w, lin_b, mxb, csrp, cursor,
            out, N, cap);
    }
}